// Round 7
// baseline (126.002 us; speedup 1.0000x reference)
//
#include <hip/hip_runtime.h>
#include <math.h>

// Adder2D: out[n,co,h,w] = -sum_{ci,kh,kw} |x[n,ci,h+kh-1,w+kw-1] - w[co,ci,kh,kw]|
// x: [16,64,32,32] f32, w: [64,64,3,3] f32, out: [16,64,32,32] f32, pad=1 stride=1.
//
// R7: saturate the LDS pipe. R6 analysis: real VALU busy ~16us (VALUBusy
// counter uses gfx94x SIMD-16 formula -> 2x inflation on SIMD-32), LDS
// inst-issue budget ~22-26us/CU -> LDS-pipe + latency bound at 4 blocks/CU.
//  - ci-split x8 (CIH=CIC=8): grid 2048 = 8 blocks/CU = 32 waves/CU (HW max).
//    LDS 17.4KB x 8 = 139KB < 160 OK; launch_bounds(256,8) holds VGPR<=64.
//  - single staging round: zero -> barrier -> stage x+w -> barrier -> 8 ci
//    straight (no round-loop serialization).
//  - 8 atomic partials/output (R6's 4 were invisible; WRITE_SIZE will tell).
//  - keep: strided pixels (u,u+8,u+16,u+24), +1-col pad, RST=40, inline-asm
//    sub+add-abs (2 insts/elem), imm-offset ds reads pairable to read2_b32.

#define N_   16
#define CI_  64
#define CO_  64
#define HW_  32
#define CG   4     // co per thread
#define COB  16    // co per block
#define PXK  4     // pixels per thread (stride 8)
#define RG   8     // pixel rows per block
#define CIH  8     // ci per block (ci-split x8)
#define RST  40    // LDS row stride in floats

__global__ __launch_bounds__(256, 8) void adder2d_kernel(
    const float* __restrict__ x, const float* __restrict__ w,
    float* __restrict__ out)
{
    __shared__ __align__(16) float xs[CIH][RG + 2][RST];   // 8*10*40*4 = 12800 B
    __shared__ __align__(16) float ws[CIH * 9 * COB];      // 8*9*16*4  =  4608 B

    const int tid   = threadIdx.x;
    const int u     = tid & 7;           // pixel cols u+8k
    const int rl    = (tid >> 3) & 7;    // pixel row
    const int cosub = tid >> 6;          // co quad (wave-uniform)
    const int r0    = blockIdx.x * RG;
    const int co0   = blockIdx.y * COB;
    const int n     = blockIdx.z & 15;
    const int ch    = blockIdx.z >> 4;   // ci eighth: ci in [8ch, 8ch+8)

    // ---- zero xs (pads persist; staged cells overwritten after barrier) ----
    for (int i = tid; i < CIH * (RG + 2) * RST / 4; i += 256)
        ((float4*)xs)[i] = float4{0.f, 0.f, 0.f, 0.f};
    __syncthreads();

    // ---- stage w for our ci-eighth: ws[(cil*9+t)*COB+cl] = w[co0+cl][ci][t] ----
    for (int i = tid; i < COB * CIH * 9; i += 256) {
        int cl  = i / (CIH * 9);
        int rem = i - cl * (CIH * 9);          // = cil*9 + t
        ws[rem * COB + cl] = w[(co0 + cl) * (CI_ * 9) + ch * (CIH * 9) + rem];
    }
    // ---- stage CIH planes, rows r0-1..r0+8 -> xs[p][rr][1+col] ----
    const float* xn = x + ((size_t)n * CI_ + ch * CIH) * (HW_ * HW_);
#pragma unroll
    for (int p = 0; p < CIH; ++p) {
        for (int i2 = tid; i2 < (RG + 2) * HW_; i2 += 256) {
            int rr  = i2 >> 5, col = i2 & 31;
            int gr  = r0 - 1 + rr;
            if ((unsigned)gr < HW_)
                xs[p][rr][1 + col] =
                    xn[(size_t)p * (HW_ * HW_) + gr * HW_ + col];
        }
    }
    __syncthreads();

    float acc[PXK][CG];
#pragma unroll
    for (int k = 0; k < PXK; ++k)
#pragma unroll
        for (int j = 0; j < CG; ++j) acc[k][j] = 0.f;

#pragma unroll 4
    for (int cil = 0; cil < CIH; ++cil) {
        const float* wr = &ws[(cil * 9) * COB + cosub * CG];

        // 9 b128 wave-broadcasts (vaddr wave-uniform)
        float4 wv[9];
#pragma unroll
        for (int t = 0; t < 9; ++t)
            wv[t] = *(const float4*)&wr[t * COB];

#pragma unroll
        for (int kh = 0; kh < 3; ++kh) {
            // padded col for pixel u+8k, tap kw is (u+8k)+kw: pad+1, tap-1 cancel
            const float* row = &xs[cil][rl + kh][u];
            float xv[PXK][3];
#pragma unroll
            for (int k = 0; k < PXK; ++k)
#pragma unroll
                for (int d = 0; d < 3; ++d)
                    xv[k][d] = row[8 * k + d];   // consecutive dwords -> ds_read2_b32

#pragma unroll
            for (int kw = 0; kw < 3; ++kw) {
                const float* wj = (const float*)&wv[kh * 3 + kw];
#pragma unroll
                for (int j = 0; j < CG; ++j)
#pragma unroll
                    for (int k = 0; k < PXK; ++k) {
                        float dd;
                        asm("v_sub_f32 %1, %2, %3\n\t"
                            "v_add_f32 %0, %0, abs(%1)"
                            : "+v"(acc[k][j]), "=&v"(dd)
                            : "v"(xv[k][kw]), "v"(wj[j]));
                    }
            }
        }
    }

    // ---- combine ci-eighths: hardware fp32 atomics into zeroed out ----
    float* op = out + (((size_t)n * CO_ + co0 + cosub * CG) * HW_ + (r0 + rl)) * HW_ + u;
#pragma unroll
    for (int j = 0; j < CG; ++j)
#pragma unroll
        for (int k = 0; k < PXK; ++k)
            unsafeAtomicAdd(&op[(size_t)j * HW_ * HW_ + 8 * k], -acc[k][j]);
}

extern "C" void kernel_launch(void* const* d_in, const int* in_sizes, int n_in,
                              void* d_out, int out_size, void* d_ws, size_t ws_size,
                              hipStream_t stream) {
    const float* x  = (const float*)d_in[0];
    const float* wp = (const float*)d_in[1];
    float* out      = (float*)d_out;
    hipMemsetAsync(d_out, 0, (size_t)out_size * sizeof(float), stream);
    dim3 grid(HW_ / RG, CO_ / COB, N_ * 8);   // (4, 4, 128) = 2048 blocks
    adder2d_kernel<<<grid, 256, 0, stream>>>(x, wp, out);
}